// Round 3
// baseline (2267.621 us; speedup 1.0000x reference)
//
#include <hip/hip_runtime.h>
#include <hip/hip_bf16.h>

typedef __bf16 bf16x8 __attribute__((ext_vector_type(8)));
typedef float f32x4 __attribute__((ext_vector_type(4)));

static constexpr int BATCH  = 8192;
static constexpr int EMBED  = 1024;
static constexpr int HIDDEN = 2048;
static constexpr int KD     = EMBED + HIDDEN;  // 3072

__device__ __forceinline__ float sigm(float x) { return 1.0f / (1.0f + __expf(-x)); }
__device__ __forceinline__ float tanh_fast(float x) { return 2.0f / (1.0f + __expf(-2.0f * x)) - 1.0f; }

// load 8 f32, convert to bf16x8 (for MFMA)
__device__ __forceinline__ bf16x8 cvt8(const float* __restrict__ p) {
  f32x4 lo = *(const f32x4*)p;
  f32x4 hi = *(const f32x4*)(p + 4);
  bf16x8 r;
  r[0] = (__bf16)lo[0]; r[1] = (__bf16)lo[1]; r[2] = (__bf16)lo[2]; r[3] = (__bf16)lo[3];
  r[4] = (__bf16)hi[0]; r[5] = (__bf16)hi[1]; r[6] = (__bf16)hi[2]; r[7] = (__bf16)hi[3];
  return r;
}

__device__ __forceinline__ unsigned pack2(float a, float b) {
  __bf16 ha = (__bf16)a, hb = (__bf16)b;
  return (unsigned)__builtin_bit_cast(unsigned short, ha) |
         ((unsigned)__builtin_bit_cast(unsigned short, hb) << 16);
}
__device__ __forceinline__ float unp2(unsigned u, int hi) {
  return __builtin_bit_cast(float, hi ? (u & 0xffff0000u) : (u << 16));
}

// ---------------- Kernel 1: fused 4-gate GEMM + LSTM cell update ----------------
// grid = (HIDDEN/128, BATCH/128), block = 256 (4 waves, 2x2 of 64x64 wave tiles)
__global__ __launch_bounds__(256) void lstm_gates_kernel(
    const float* __restrict__ x, const float* __restrict__ st, const float* __restrict__ lt,
    const float* __restrict__ Wf, const float* __restrict__ bfp,
    const float* __restrict__ Wi, const float* __restrict__ bip,
    const float* __restrict__ Wc, const float* __restrict__ bcp,
    const float* __restrict__ Wo, const float* __restrict__ bop,
    float* __restrict__ out1 /* o stash -> final output buffer */,
    float* __restrict__ out2 /* C_new, f32 */)
{
  __shared__ __align__(16) __bf16 sA[128 * 32];
  __shared__ __align__(16) __bf16 sB[128 * 32];

  const int tid  = threadIdx.x;
  const int lane = tid & 63;
  const int wave = tid >> 6;
  const int waveM = wave >> 1;
  const int waveN = wave & 1;

  const int row0 = blockIdx.y * 128;  // batch tile
  const int n0   = blockIdx.x * 128;  // hidden tile

  // staging mapping: tile-row = tid/4 (0..63), 8-elem chunk = tid%4
  const int r_st = tid >> 2;
  const int c8   = (tid & 3) * 8;
  const size_t aX0 = (size_t)(row0 + r_st) * EMBED + c8;
  const size_t aX1 = (size_t)(row0 + 64 + r_st) * EMBED + c8;
  const size_t aS0 = (size_t)(row0 + r_st) * HIDDEN + c8;
  const size_t aS1 = (size_t)(row0 + 64 + r_st) * HIDDEN + c8;
  const size_t w0  = (size_t)(n0 + r_st) * KD + c8;
  const size_t w1  = (size_t)(n0 + 64 + r_st) * KD + c8;
  const int stLo = r_st * 32 + c8;   // LDS element offset, tile rows 0..63
  const int stHi = 2048 + stLo;      // tile rows 64..127

  // fragment reads; A[m][k]: m=lane&15, k=(lane>>4)*8+j (m92/m97 verified)
  const int kr = (lane >> 4) * 8;
  const int rA = (waveM * 64 + (lane & 15)) * 32 + kr;
  const int rB = (waveN * 64 + (lane & 15)) * 32 + kr;

  f32x4 acc[4][4];

  auto kloop = [&](const float* __restrict__ W) {
#pragma unroll
    for (int fm = 0; fm < 4; ++fm)
#pragma unroll
      for (int fn = 0; fn < 4; ++fn)
        acc[fm][fn] = (f32x4){0.f, 0.f, 0.f, 0.f};

    for (int k0 = 0; k0 < KD; k0 += 32) {
      bf16x8 va0, va1;
      if (k0 < EMBED) {
        va0 = cvt8(x + aX0 + k0);
        va1 = cvt8(x + aX1 + k0);
      } else {
        const int kk = k0 - EMBED;
        va0 = cvt8(st + aS0 + kk);
        va1 = cvt8(st + aS1 + kk);
      }
      bf16x8 vb0 = cvt8(W + w0 + k0);
      bf16x8 vb1 = cvt8(W + w1 + k0);

      __syncthreads();  // all waves' prior ds_reads done (lgkmcnt(0) before barrier)
      *(bf16x8*)(sA + stLo) = va0;
      *(bf16x8*)(sA + stHi) = va1;
      *(bf16x8*)(sB + stLo) = vb0;
      *(bf16x8*)(sB + stHi) = vb1;
      __syncthreads();  // writes visible

      bf16x8 a[4], b[4];
#pragma unroll
      for (int f = 0; f < 4; ++f) {
        a[f] = *(const bf16x8*)(sA + rA + f * 16 * 32);
        b[f] = *(const bf16x8*)(sB + rB + f * 16 * 32);
      }
#pragma unroll
      for (int fm = 0; fm < 4; ++fm)
#pragma unroll
        for (int fn = 0; fn < 4; ++fn)
          acc[fm][fn] = __builtin_amdgcn_mfma_f32_16x16x32_bf16(a[fm], b[fn], acc[fm][fn], 0, 0, 0);
    }
  };

  // C/D layout (m89/m91 verified): col = lane&15, row = (lane>>4)*4 + reg
  const int colB = n0 + waveN * 64 + (lane & 15);
  const int rowB = row0 + waveM * 64 + ((lane >> 4) << 2);

  unsigned cn_pk[4][4][2];  // f*long_term, bf16-packed
  unsigned i_pk[4][4][2];   // i gate, bf16-packed

  // ---- gate f: stash f*long_term ----
  kloop(Wf);
#pragma unroll
  for (int fn = 0; fn < 4; ++fn) {
    const int col = colB + fn * 16;
    const float bv = bfp[col];
#pragma unroll
    for (int fm = 0; fm < 4; ++fm) {
      float c_[4];
#pragma unroll
      for (int rr = 0; rr < 4; ++rr) {
        const int row = rowB + fm * 16 + rr;
        const float fg = sigm(acc[fm][fn][rr] + bv);
        c_[rr] = fg * lt[(size_t)row * HIDDEN + col];
      }
      cn_pk[fm][fn][0] = pack2(c_[0], c_[1]);
      cn_pk[fm][fn][1] = pack2(c_[2], c_[3]);
    }
  }

  // ---- gate i: stash sigmoid ----
  kloop(Wi);
#pragma unroll
  for (int fn = 0; fn < 4; ++fn) {
    const int col = colB + fn * 16;
    const float bv = bip[col];
#pragma unroll
    for (int fm = 0; fm < 4; ++fm) {
      float c_[4];
#pragma unroll
      for (int rr = 0; rr < 4; ++rr)
        c_[rr] = sigm(acc[fm][fn][rr] + bv);
      i_pk[fm][fn][0] = pack2(c_[0], c_[1]);
      i_pk[fm][fn][1] = pack2(c_[2], c_[3]);
    }
  }

  // ---- gate c: C_new = f*lt + i*tanh(c~)  -> out2 (f32) ----
  kloop(Wc);
#pragma unroll
  for (int fn = 0; fn < 4; ++fn) {
    const int col = colB + fn * 16;
    const float bv = bcp[col];
#pragma unroll
    for (int fm = 0; fm < 4; ++fm) {
#pragma unroll
      for (int rr = 0; rr < 4; ++rr) {
        const int row = rowB + fm * 16 + rr;
        const float ct = tanh_fast(acc[fm][fn][rr] + bv);
        const float cn = unp2(cn_pk[fm][fn][rr >> 1], rr & 1)
                       + unp2(i_pk[fm][fn][rr >> 1], rr & 1) * ct;
        out2[(size_t)row * HIDDEN + col] = cn;
      }
    }
  }

  // ---- gate o: stash sigmoid into out1 (f32; overwritten by kernel 2) ----
  kloop(Wo);
#pragma unroll
  for (int fn = 0; fn < 4; ++fn) {
    const int col = colB + fn * 16;
    const float bv = bop[col];
#pragma unroll
    for (int fm = 0; fm < 4; ++fm) {
#pragma unroll
      for (int rr = 0; rr < 4; ++rr) {
        const int row = rowB + fm * 16 + rr;
        out1[(size_t)row * HIDDEN + col] = sigm(acc[fm][fn][rr] + bv);
      }
    }
  }
}

// ---------------- Kernel 2: output = tanh(C_new @ W_h2o^T + b) * o ----------------
__global__ __launch_bounds__(256) void lstm_out_kernel(
    const float* __restrict__ cn, const float* __restrict__ Wh, const float* __restrict__ bh,
    float* __restrict__ out1)
{
  __shared__ __align__(16) __bf16 sA[128 * 32];
  __shared__ __align__(16) __bf16 sB[128 * 32];

  const int tid  = threadIdx.x;
  const int lane = tid & 63;
  const int wave = tid >> 6;
  const int waveM = wave >> 1;
  const int waveN = wave & 1;

  const int row0 = blockIdx.y * 128;
  const int n0   = blockIdx.x * 128;

  const int r_st = tid >> 2;
  const int c8   = (tid & 3) * 8;
  const size_t a0 = (size_t)(row0 + r_st) * HIDDEN + c8;
  const size_t a1 = (size_t)(row0 + 64 + r_st) * HIDDEN + c8;
  const size_t w0 = (size_t)(n0 + r_st) * HIDDEN + c8;
  const size_t w1 = (size_t)(n0 + 64 + r_st) * HIDDEN + c8;
  const int stLo = r_st * 32 + c8;
  const int stHi = 2048 + stLo;

  const int kr = (lane >> 4) * 8;
  const int rA = (waveM * 64 + (lane & 15)) * 32 + kr;
  const int rB = (waveN * 64 + (lane & 15)) * 32 + kr;

  f32x4 acc[4][4];
#pragma unroll
  for (int fm = 0; fm < 4; ++fm)
#pragma unroll
    for (int fn = 0; fn < 4; ++fn)
      acc[fm][fn] = (f32x4){0.f, 0.f, 0.f, 0.f};

  for (int k0 = 0; k0 < HIDDEN; k0 += 32) {
    bf16x8 va0 = cvt8(cn + a0 + k0);
    bf16x8 va1 = cvt8(cn + a1 + k0);
    bf16x8 vb0 = cvt8(Wh + w0 + k0);
    bf16x8 vb1 = cvt8(Wh + w1 + k0);

    __syncthreads();
    *(bf16x8*)(sA + stLo) = va0;
    *(bf16x8*)(sA + stHi) = va1;
    *(bf16x8*)(sB + stLo) = vb0;
    *(bf16x8*)(sB + stHi) = vb1;
    __syncthreads();

    bf16x8 a[4], b[4];
#pragma unroll
    for (int f = 0; f < 4; ++f) {
      a[f] = *(const bf16x8*)(sA + rA + f * 16 * 32);
      b[f] = *(const bf16x8*)(sB + rB + f * 16 * 32);
    }
#pragma unroll
    for (int fm = 0; fm < 4; ++fm)
#pragma unroll
      for (int fn = 0; fn < 4; ++fn)
        acc[fm][fn] = __builtin_amdgcn_mfma_f32_16x16x32_bf16(a[fm], b[fn], acc[fm][fn], 0, 0, 0);
  }

  const int colB = n0 + waveN * 64 + (lane & 15);
  const int rowB = row0 + waveM * 64 + ((lane >> 4) << 2);
#pragma unroll
  for (int fn = 0; fn < 4; ++fn) {
    const int col = colB + fn * 16;
    const float bv = bh[col];
#pragma unroll
    for (int fm = 0; fm < 4; ++fm) {
#pragma unroll
      for (int rr = 0; rr < 4; ++rr) {
        const int row = rowB + fm * 16 + rr;
        const size_t idx = (size_t)row * HIDDEN + col;
        const float v = tanh_fast(acc[fm][fn][rr] + bv);
        const float ov = out1[idx];  // o gate stashed by kernel 1
        out1[idx] = v * ov;
      }
    }
  }
}

extern "C" void kernel_launch(void* const* d_in, const int* in_sizes, int n_in,
                              void* d_out, int out_size, void* d_ws, size_t ws_size,
                              hipStream_t stream) {
  const float* x   = (const float*)d_in[0];
  const float* st  = (const float*)d_in[1];
  const float* lt  = (const float*)d_in[2];
  const float* Wf  = (const float*)d_in[3];
  const float* bfp = (const float*)d_in[4];
  const float* Wi  = (const float*)d_in[5];
  const float* bip = (const float*)d_in[6];
  const float* Wc  = (const float*)d_in[7];
  const float* bcp = (const float*)d_in[8];
  const float* Wo  = (const float*)d_in[9];
  const float* bop = (const float*)d_in[10];
  const float* Wh  = (const float*)d_in[11];
  const float* bh  = (const float*)d_in[12];

  float* out1 = (float*)d_out;                        // output [B,H] f32
  float* out2 = out1 + (size_t)BATCH * HIDDEN;        // C_new [B,H] f32

  dim3 grid(HIDDEN / 128, BATCH / 128);  // (16, 64)
  lstm_gates_kernel<<<grid, 256, 0, stream>>>(x, st, lt, Wf, bfp, Wi, bip, Wc, bcp, Wo, bop, out1, out2);
  lstm_out_kernel<<<grid, 256, 0, stream>>>(out2, Wh, bh, out1);
}